// Round 1
// baseline (258.790 us; speedup 1.0000x reference)
//
#include <hip/hip_runtime.h>
#include <math.h>

constexpr int T_TOTAL = 16777216;   // 2^24
constexpr int TPB     = 256;
constexpr int EPT     = 16;                 // elements per thread
constexpr int CHUNK   = TPB * EPT;          // 4096 elements per block
constexpr int NB      = T_TOTAL / CHUNK;    // 4096 blocks
constexpr float THRESHOLD = 0.5f;

// exclusive block-scan of per-thread value s (256 threads, 4 waves of 64)
__device__ __forceinline__ int block_exscan(int s, int* wsum) {
    const int lane = threadIdx.x & 63;
    const int wid  = threadIdx.x >> 6;
    int x = s;
    #pragma unroll
    for (int d = 1; d < 64; d <<= 1) {
        int y = __shfl_up(x, d);
        if (lane >= d) x += y;
    }
    if (lane == 63) wsum[wid] = x;
    __syncthreads();
    int wbase = 0;
    #pragma unroll
    for (int w = 0; w < 3; w++) if (w < wid) wbase += wsum[w];
    return wbase + (x - s);   // exclusive prefix for this thread
}

// Pass 1: per-block sums of net = onsets - offsets
__global__ void __launch_bounds__(TPB)
k_blocksums(const int4* __restrict__ on4, const int4* __restrict__ off4,
            int* __restrict__ bsums) {
    const int b = blockIdx.x;
    const int tbase = (b * CHUNK + threadIdx.x * EPT) >> 2;  // int4 index
    int s = 0;
    #pragma unroll
    for (int i = 0; i < EPT / 4; i++) {
        int4 a = on4[tbase + i];
        int4 c = off4[tbase + i];
        s += (a.x + a.y + a.z + a.w) - (c.x + c.y + c.z + c.w);
    }
    #pragma unroll
    for (int d = 32; d > 0; d >>= 1) s += __shfl_xor(s, d);
    __shared__ int ws[4];
    if ((threadIdx.x & 63) == 0) ws[threadIdx.x >> 6] = s;
    __syncthreads();
    if (threadIdx.x == 0) bsums[b] = ws[0] + ws[1] + ws[2] + ws[3];
}

// Pass 2: in-place exclusive scan of the NB block sums (single block)
__global__ void __launch_bounds__(TPB)
k_scan(int* __restrict__ bsums) {
    __shared__ int wsum[4];
    int vals[NB / TPB];
    const int base = threadIdx.x * (NB / TPB);
    int s = 0;
    #pragma unroll
    for (int i = 0; i < NB / TPB; i++) { vals[i] = bsums[base + i]; s += vals[i]; }
    int ex = block_exscan(s, wsum);
    #pragma unroll
    for (int i = 0; i < NB / TPB; i++) { int v = vals[i]; bsums[base + i] = ex; ex += v; }
}

// Pass 3: recompute intra-block prefix, count active & over-threshold
__global__ void __launch_bounds__(TPB)
k_main(const int4* __restrict__ on4, const int4* __restrict__ off4,
       const float4* __restrict__ u4, const float4* __restrict__ e4,
       const int* __restrict__ bprefix, int* __restrict__ counters) {
    const int b = blockIdx.x;
    const int elem0 = b * CHUNK + threadIdx.x * EPT;
    int net[EPT];
    const int tbase = elem0 >> 2;
    int s = 0;
    #pragma unroll
    for (int i = 0; i < EPT / 4; i++) {
        int4 a = on4[tbase + i];
        int4 c = off4[tbase + i];
        net[4 * i + 0] = a.x - c.x;
        net[4 * i + 1] = a.y - c.y;
        net[4 * i + 2] = a.z - c.z;
        net[4 * i + 3] = a.w - c.w;
        s += net[4 * i + 0] + net[4 * i + 1] + net[4 * i + 2] + net[4 * i + 3];
    }
    __shared__ int wscan[4];
    const int ex = block_exscan(s, wscan);
    int prefix = bprefix[b] + ex;

    int cover = 0, cact = 0;
    const int fbase = elem0 >> 1;   // float4 index: element t -> floats [2t, 2t+1]
    #pragma unroll
    for (int i = 0; i < EPT / 2; i++) {
        float4 uv = u4[fbase + i];
        float4 ev = e4[fbase + i];
        // element 2i -> lanes .x (col 0), element 2i+1 -> .z (col 0)
        prefix += net[2 * i];
        if (prefix > 0) { cact++; if (fabsf(ev.x - uv.x) > THRESHOLD) cover++; }
        prefix += net[2 * i + 1];
        if (prefix > 0) { cact++; if (fabsf(ev.z - uv.z) > THRESHOLD) cover++; }
    }

    #pragma unroll
    for (int d = 32; d > 0; d >>= 1) {
        cover += __shfl_xor(cover, d);
        cact  += __shfl_xor(cact, d);
    }
    __shared__ int wc[4], wa[4];
    if ((threadIdx.x & 63) == 0) { wc[threadIdx.x >> 6] = cover; wa[threadIdx.x >> 6] = cact; }
    __syncthreads();
    if (threadIdx.x == 0) {
        atomicAdd(&counters[0], wc[0] + wc[1] + wc[2] + wc[3]);
        atomicAdd(&counters[1], wa[0] + wa[1] + wa[2] + wa[3]);
    }
}

__global__ void k_final(const int* __restrict__ counters, float* __restrict__ out) {
    out[0] = (float)counters[0] / (float)counters[1];
}

extern "C" void kernel_launch(void* const* d_in, const int* in_sizes, int n_in,
                              void* d_out, int out_size, void* d_ws, size_t ws_size,
                              hipStream_t stream) {
    const float* u  = (const float*)d_in[0];
    const float* e  = (const float*)d_in[1];
    const int*   on = (const int*)d_in[2];
    const int*   off= (const int*)d_in[3];

    int* counters = (int*)d_ws;        // [0]=count_over, [1]=count_active
    int* bsums    = counters + 4;      // NB ints, keeps 16B alignment

    hipMemsetAsync(counters, 0, 2 * sizeof(int), stream);
    k_blocksums<<<NB, TPB, 0, stream>>>((const int4*)on, (const int4*)off, bsums);
    k_scan<<<1, TPB, 0, stream>>>(bsums);
    k_main<<<NB, TPB, 0, stream>>>((const int4*)on, (const int4*)off,
                                   (const float4*)u, (const float4*)e,
                                   bsums, counters);
    k_final<<<1, 1, 0, stream>>>(counters, (float*)d_out);
}

// Round 3
// 112.960 us; speedup vs baseline: 2.2910x; 2.2910x over previous
//
#include <hip/hip_runtime.h>
#include <math.h>

constexpr int T_TOTAL = 16777216;            // 2^24
constexpr int TPB     = 256;
constexpr int CHUNK   = 16384;               // elements per block
constexpr int NB      = T_TOTAL / CHUNK;     // 1024 blocks
constexpr int WORDS   = CHUNK / 4;           // 4096 packed char4 words per block
constexpr int EPT     = CHUNK / TPB;         // 64 elements per thread (scan phase)
constexpr float THRESHOLD = 0.5f;

__device__ __forceinline__ int swz(int w) { return w ^ ((w >> 5) & 31); }

// exclusive block-scan of per-thread value s (256 threads, 4 waves of 64)
__device__ __forceinline__ int block_exscan(int s, int* wsum) {
    const int lane = threadIdx.x & 63;
    const int wid  = threadIdx.x >> 6;
    int x = s;
    #pragma unroll
    for (int d = 1; d < 64; d <<= 1) {
        int y = __shfl_up(x, d);
        if (lane >= d) x += y;
    }
    if (lane == 63) wsum[wid] = x;
    __syncthreads();
    int wbase = 0;
    #pragma unroll
    for (int w = 0; w < 3; w++) if (w < wid) wbase += wsum[w];
    return wbase + (x - s);
}

// Pass 1: per-block sums of net = onsets - offsets (fully coalesced)
__global__ void __launch_bounds__(TPB)
k_blocksums(const int4* __restrict__ on4, const int4* __restrict__ off4,
            int* __restrict__ bsums) {
    const int base = blockIdx.x * WORDS;
    int s = 0;
    #pragma unroll
    for (int r = 0; r < WORDS / TPB; r++) {          // 16 rounds
        int4 a = on4[base + r * TPB + threadIdx.x];
        int4 c = off4[base + r * TPB + threadIdx.x];
        s += (a.x + a.y + a.z + a.w) - (c.x + c.y + c.z + c.w);
    }
    #pragma unroll
    for (int d = 32; d > 0; d >>= 1) s += __shfl_xor(s, d);
    __shared__ int ws[4];
    if ((threadIdx.x & 63) == 0) ws[threadIdx.x >> 6] = s;
    __syncthreads();
    if (threadIdx.x == 0) bsums[blockIdx.x] = ws[0] + ws[1] + ws[2] + ws[3];
}

// Pass 2: exclusive scan of NB block sums (single block)
__global__ void __launch_bounds__(TPB)
k_scan(int* __restrict__ bsums) {
    __shared__ int wsum[4];
    int vals[NB / TPB];
    const int base = threadIdx.x * (NB / TPB);
    int s = 0;
    #pragma unroll
    for (int i = 0; i < NB / TPB; i++) { vals[i] = bsums[base + i]; s += vals[i]; }
    int ex = block_exscan(s, wsum);
    #pragma unroll
    for (int i = 0; i < NB / TPB; i++) { int v = vals[i]; bsums[base + i] = ex; ex += v; }
}

// Pass 3: coalesced loads + LDS transpose scan + coalesced u/e count
__global__ void __launch_bounds__(TPB)
k_main(const int4* __restrict__ on4, const int4* __restrict__ off4,
       const float4* __restrict__ u4, const float4* __restrict__ e4,
       const int* __restrict__ bprefix, int* __restrict__ counters) {
    __shared__ int sh_net[WORDS];                     // 16 KB, swizzled
    __shared__ unsigned long long sh_act[TPB];        // 2 KB active bitmasks
    __shared__ int wscan[4];

    const int b   = blockIdx.x;
    const int tid = threadIdx.x;

    // Phase 1: coalesced on/off load, pack net as char4 into swizzled LDS
    const int gbase = b * WORDS;                      // int4 index
    #pragma unroll
    for (int r = 0; r < WORDS / TPB; r++) {           // 16 rounds
        const int w = r * TPB + tid;                  // word index in block
        int4 a = on4[gbase + w];
        int4 c = off4[gbase + w];
        int n0 = a.x - c.x, n1 = a.y - c.y, n2 = a.z - c.z, n3 = a.w - c.w;
        int packed = (n0 & 0xff) | ((n1 & 0xff) << 8) |
                     ((n2 & 0xff) << 16) | (n3 << 24);
        sh_net[swz(w)] = packed;
    }
    __syncthreads();

    // Phase 2: per-thread contiguous 64 nets from LDS, thread sum, block exscan
    int my[EPT / 4];                                  // 16 packed words
    int s = 0;
    #pragma unroll
    for (int m = 0; m < EPT / 4; m++) {
        int wv = sh_net[swz(tid * (EPT / 4) + m)];
        my[m] = wv;
        s += (int)(char)(wv) + (int)(char)(wv >> 8) +
             (int)(char)(wv >> 16) + (int)(char)(wv >> 24);
    }
    const int ex = block_exscan(s, wscan);
    int p = bprefix[b] + ex;

    // Phase 3: running prefix -> active bitmask
    unsigned long long mask = 0;
    #pragma unroll
    for (int m = 0; m < EPT / 4; m++) {
        int wv = my[m];
        #pragma unroll
        for (int k = 0; k < 4; k++) {
            p += (int)(char)(wv >> (8 * k));
            if (p > 0) mask |= 1ull << (m * 4 + k);
        }
    }
    sh_act[tid] = mask;
    __syncthreads();

    // Phase 4: coalesced u/e count (float4 = 2 elements: .x and .z are col 0)
    const int fbase = b * (CHUNK / 2);                // float4 index
    int cover = 0, cact = 0;
    #pragma unroll 4
    for (int r = 0; r < CHUNK / (2 * TPB); r++) {     // 32 rounds
        const int k = r * TPB + tid;                  // covers elements 2k, 2k+1
        float4 uv = u4[fbase + k];
        float4 ev = e4[fbase + k];
        unsigned long long m = sh_act[k >> 5];        // broadcast per half-wave
        const int bit = (k & 31) * 2;
        const int a0 = (int)((m >> bit) & 1);
        const int a1 = (int)((m >> (bit + 1)) & 1);
        cact += a0 + a1;
        if (a0 && fabsf(ev.x - uv.x) > THRESHOLD) cover++;
        if (a1 && fabsf(ev.z - uv.z) > THRESHOLD) cover++;
    }

    #pragma unroll
    for (int d = 32; d > 0; d >>= 1) {
        cover += __shfl_xor(cover, d);
        cact  += __shfl_xor(cact, d);
    }
    __shared__ int wc[4], wa[4];
    if ((tid & 63) == 0) { wc[tid >> 6] = cover; wa[tid >> 6] = cact; }
    __syncthreads();
    if (tid == 0) {
        atomicAdd(&counters[0], wc[0] + wc[1] + wc[2] + wc[3]);
        atomicAdd(&counters[1], wa[0] + wa[1] + wa[2] + wa[3]);
    }
}

__global__ void k_final(const int* __restrict__ counters, float* __restrict__ out) {
    out[0] = (float)counters[0] / (float)counters[1];
}

extern "C" void kernel_launch(void* const* d_in, const int* in_sizes, int n_in,
                              void* d_out, int out_size, void* d_ws, size_t ws_size,
                              hipStream_t stream) {
    const float* u   = (const float*)d_in[0];
    const float* e   = (const float*)d_in[1];
    const int*   on  = (const int*)d_in[2];
    const int*   off = (const int*)d_in[3];

    int* counters = (int*)d_ws;        // [0]=count_over, [1]=count_active
    int* bsums    = counters + 4;      // NB ints

    hipMemsetAsync(counters, 0, 2 * sizeof(int), stream);
    k_blocksums<<<NB, TPB, 0, stream>>>((const int4*)on, (const int4*)off, bsums);
    k_scan<<<1, TPB, 0, stream>>>(bsums);
    k_main<<<NB, TPB, 0, stream>>>((const int4*)on, (const int4*)off,
                                   (const float4*)u, (const float4*)e,
                                   bsums, counters);
    k_final<<<1, 1, 0, stream>>>(counters, (float*)d_out);
}

// Round 6
// 93.758 us; speedup vs baseline: 2.7602x; 1.2048x over previous
//
#include <hip/hip_runtime.h>
#include <math.h>

constexpr int T_TOTAL = 16777216;          // 2^24
constexpr int TPB     = 256;               // 4 waves per block
constexpr int SEG     = 2048;              // elements per wave segment
constexpr int NSEG    = T_TOTAL / SEG;     // 8192 segments
constexpr int NBLK    = NSEG / 4;          // 2048 blocks
constexpr int ITERS   = SEG / 128;         // 16 iterations per wave
constexpr float THRESHOLD = 0.5f;

// Pass 1: per-segment net sums (fully coalesced, no LDS)
__global__ void __launch_bounds__(TPB)
k_segsums(const int2* __restrict__ on2, const int2* __restrict__ off2,
          int* __restrict__ segsums) {
    const int lane = threadIdx.x & 63;
    const int wid  = threadIdx.x >> 6;
    const int seg  = blockIdx.x * 4 + wid;
    const int base = seg * (SEG / 2);          // int2 index
    int s = 0;
    #pragma unroll
    for (int it = 0; it < ITERS; ++it) {
        int2 a = on2[base + it * 64 + lane];
        int2 c = off2[base + it * 64 + lane];
        s += a.x + a.y - c.x - c.y;
    }
    #pragma unroll
    for (int d = 32; d > 0; d >>= 1) s += __shfl_xor(s, d);
    if (lane == 0) segsums[seg] = s;
}

// Pass 2: exclusive scan of NSEG segment sums (single block, 32/thread)
__global__ void __launch_bounds__(TPB)
k_scan(int* __restrict__ segsums) {
    __shared__ int wsum[4];
    const int lane = threadIdx.x & 63;
    const int wid  = threadIdx.x >> 6;
    int vals[NSEG / TPB];
    const int base = threadIdx.x * (NSEG / TPB);
    int s = 0;
    #pragma unroll
    for (int i = 0; i < NSEG / TPB; i++) { vals[i] = segsums[base + i]; s += vals[i]; }
    // block exclusive scan of s
    int x = s;
    #pragma unroll
    for (int d = 1; d < 64; d <<= 1) {
        int y = __shfl_up(x, d);
        if (lane >= d) x += y;
    }
    if (lane == 63) wsum[wid] = x;
    __syncthreads();
    int wbase = 0;
    #pragma unroll
    for (int w = 0; w < 3; w++) if (w < wid) wbase += wsum[w];
    int ex = wbase + (x - s);
    #pragma unroll
    for (int i = 0; i < NSEG / TPB; i++) { int v = vals[i]; segsums[base + i] = ex; ex += v; }
}

// Pass 3: ballot-based active mask + count. Fully independent waves, no LDS
// in the hot loop. Lane i of each 128-element iteration handles elements
// 2i and 2i+1: int2 index == float4 index == base + it*64 + lane.
__global__ void __launch_bounds__(TPB)
k_count(const int2* __restrict__ on2, const int2* __restrict__ off2,
        const float4* __restrict__ u4, const float4* __restrict__ e4,
        const int* __restrict__ segpre, int2* __restrict__ partials) {
    const int lane = threadIdx.x & 63;
    const int wid  = threadIdx.x >> 6;
    const int seg  = blockIdx.x * 4 + wid;
    const int base = seg * (SEG / 2);
    const unsigned long long le = (~0ull) >> (63 - lane);   // lanes 0..i
    const unsigned long long lt = le >> 1;                  // lanes 0..i-1

    int basep = segpre[seg];     // exclusive prefix of net before this segment
    int cover = 0, cact = 0;

    #pragma unroll 4
    for (int it = 0; it < ITERS; ++it) {
        const int idx = base + it * 64 + lane;
        int2   a  = on2[idx];
        int2   c  = off2[idx];
        float4 uv = u4[idx];
        float4 ev = e4[idx];

        unsigned long long be_on  = __ballot(a.x != 0);  // evens: elements 2i
        unsigned long long bo_on  = __ballot(a.y != 0);  // odds:  elements 2i+1
        unsigned long long be_off = __ballot(c.x != 0);
        unsigned long long bo_off = __ballot(c.y != 0);

        const int de = __popcll(be_on & le) - __popcll(be_off & le);
        const int pe = basep + de + __popcll(bo_on & lt) - __popcll(bo_off & lt);
        const int po = basep + de + __popcll(bo_on & le) - __popcll(bo_off & le);
        basep += __popcll(be_on) - __popcll(be_off)
               + __popcll(bo_on) - __popcll(bo_off);

        const int a0 = pe > 0, a1 = po > 0;
        cact += a0 + a1;
        if (a0 && fabsf(ev.x - uv.x) > THRESHOLD) cover++;   // col 0 of elem 2i
        if (a1 && fabsf(ev.z - uv.z) > THRESHOLD) cover++;   // col 0 of elem 2i+1
    }

    #pragma unroll
    for (int d = 32; d > 0; d >>= 1) {
        cover += __shfl_xor(cover, d);
        cact  += __shfl_xor(cact, d);
    }
    __shared__ int sc[4], sa[4];
    if (lane == 0) { sc[wid] = cover; sa[wid] = cact; }
    __syncthreads();
    if (threadIdx.x == 0)
        partials[blockIdx.x] = make_int2(sc[0] + sc[1] + sc[2] + sc[3],
                                         sa[0] + sa[1] + sa[2] + sa[3]);
}

// Pass 4: reduce block partials, divide
__global__ void __launch_bounds__(TPB)
k_final(const int2* __restrict__ partials, float* __restrict__ out) {
    const int lane = threadIdx.x & 63;
    const int wid  = threadIdx.x >> 6;
    int c = 0, a = 0;
    for (int i = threadIdx.x; i < NBLK; i += TPB) {
        int2 p = partials[i];
        c += p.x; a += p.y;
    }
    #pragma unroll
    for (int d = 32; d > 0; d >>= 1) {
        c += __shfl_xor(c, d);
        a += __shfl_xor(a, d);
    }
    __shared__ int sc[4], sa[4];
    if (lane == 0) { sc[wid] = c; sa[wid] = a; }
    __syncthreads();
    if (threadIdx.x == 0) {
        float ctot = (float)(sc[0] + sc[1] + sc[2] + sc[3]);
        float atot = (float)(sa[0] + sa[1] + sa[2] + sa[3]);
        out[0] = ctot / atot;
    }
}

extern "C" void kernel_launch(void* const* d_in, const int* in_sizes, int n_in,
                              void* d_out, int out_size, void* d_ws, size_t ws_size,
                              hipStream_t stream) {
    const float* u   = (const float*)d_in[0];
    const float* e   = (const float*)d_in[1];
    const int*   on  = (const int*)d_in[2];
    const int*   off = (const int*)d_in[3];

    int*  segsums  = (int*)d_ws;                 // NSEG ints (32 KB)
    int2* partials = (int2*)(segsums + NSEG);    // NBLK int2 (16 KB)

    k_segsums<<<NBLK, TPB, 0, stream>>>((const int2*)on, (const int2*)off, segsums);
    k_scan<<<1, TPB, 0, stream>>>(segsums);
    k_count<<<NBLK, TPB, 0, stream>>>((const int2*)on, (const int2*)off,
                                      (const float4*)u, (const float4*)e,
                                      segsums, partials);
    k_final<<<1, TPB, 0, stream>>>(partials, (float*)d_out);
}